// Round 7
// baseline (66.134 us; speedup 1.0000x reference)
//
#include <hip/hip_runtime.h>
#include <hip/hip_bf16.h>

// SparseProtoLinear: S=131072 tokens, D=64, P=8 experts.
// d_out = [y (S*64) | logits (S*8) | mask (S*8)], fp32.
//
// prep_w: fp32 W1/W2 -> bf16 image in d_ws (XOR-swizzled rows; W2 columns
//         permuted so GEMM2 A-frags read as b128).
// spl_main: 512 blocks x 512 thr, 256 tokens/block (32/wave).
//   LDS = 64KB (4 experts) + 8KB wt table -> 72KB => 2 blocks/CU
//   (16 waves/CU, 4/SIMD — round 6 had 2/SIMD; this is the lever).
//   Two passes of 4 experts; restage between passes. Expert loop itself
//   barrier-free. GEMM1 swapped (W1 x X^T, mfma 16x16x32), silu*wt packed
//   in-register -> GEMM2 (mfma 16x16x16) accumulates into yacc.
//   Epilogue: yacc -> LDS -> full-cacheline 1KB y stores.

typedef __attribute__((ext_vector_type(8))) short short8;
typedef __attribute__((ext_vector_type(4))) short bf16x4;   // HIP owns `short4`
typedef __attribute__((ext_vector_type(4))) float f32x4;
typedef __attribute__((ext_vector_type(4))) unsigned int u32x4;
typedef __attribute__((ext_vector_type(2))) unsigned int u32x2;

#define NEXP 8
#define DH 64
#define BT 256
#define THREADS 512
#define OFF_WT 65536
#define LDS_BYTES (65536 + 8192)   // 4-expert W buffer + 256x8 wt table

__device__ __forceinline__ unsigned int f2bf(float f) {
    unsigned int u = __builtin_bit_cast(unsigned int, f);
    return (u + 0x7fffu + ((u >> 16) & 1u)) >> 16;  // RTNE (prep kernel only)
}
__device__ __forceinline__ short bfc(float f) {     // compiler-lowered convert
    return (short)__bfloat16_as_ushort(__float2bfloat16(f));
}

#if __has_builtin(__builtin_amdgcn_mfma_f32_16x16x16_bf16)
#define MFMA16(a, b, c) __builtin_amdgcn_mfma_f32_16x16x16_bf16(a, b, c, 0, 0, 0)
#else
#define MFMA16(a, b, c) __builtin_amdgcn_mfma_f32_16x16x16bf16_1k(a, b, c, 0, 0, 0)
#endif

typedef const unsigned int __attribute__((address_space(1)))* gas_u32p;
typedef unsigned int __attribute__((address_space(3)))* las_u32p;

// g includes the per-lane offset; lbase is wave-uniform (HW adds lane*16).
__device__ __forceinline__ void glds16(const void* g, void* lbase, int lane) {
#if __has_builtin(__builtin_amdgcn_global_load_lds)
    (void)lane;
    __builtin_amdgcn_global_load_lds((gas_u32p)g, (las_u32p)lbase, 16, 0, 0);
#else
    *reinterpret_cast<u32x4*>(reinterpret_cast<char*>(lbase) + lane * 16) =
        *reinterpret_cast<const u32x4*>(g);
#endif
}

// ---------------- prep: weights -> bf16 swizzled image (128 KiB) ----------------
__global__ void prep_w(const float* __restrict__ w1, const float* __restrict__ w2,
                       unsigned char* __restrict__ ws) {
    int q = blockIdx.x * 256 + threadIdx.x;          // 16384 quads of 4 f32
    int mat = q >> 13;                               // 0=W1, 1=W2
    int p = (q >> 10) & 7;
    int r = (q >> 4) & 63;                           // source row (o for W1, d for W2)
    int dq = q & 15;                                 // source col quad
    const float* src = (mat ? w2 : w1) + (size_t)(((p << 6) + r) << 6) + (dq << 2);
    f32x4 v = *reinterpret_cast<const f32x4*>(src);
    u32x2 pk;
    pk[0] = f2bf(v[0]) | (f2bf(v[1]) << 16);
    pk[1] = f2bf(v[2]) | (f2bf(v[3]) << 16);
    // W1: byte col = dq*8.  W2 col-permute o=[mp|fg|j]->[fg|mp|j]:
    //   mp=dq>>2, fg=dq&3 -> byte col = fg*32 + mp*8.
    int col = mat ? (((dq & 3) << 5) | ((dq >> 2) << 3)) : (dq << 3);
    int off = (p << 14) + (mat << 13) + (r << 7) + (col ^ ((r & 7) << 4));
    *reinterpret_cast<u32x2*>(ws + off) = pk;
}

// ---------------- main fused kernel ----------------
__global__ __launch_bounds__(THREADS, 4)          // cap VGPR at 128 -> 2 blocks/CU
void spl_main(const float* __restrict__ x, const float* __restrict__ proto,
              const float* __restrict__ gate, const unsigned char* __restrict__ wimg,
              float* __restrict__ y_out, float* __restrict__ logits_out,
              float* __restrict__ mask_out)
{
    extern __shared__ __align__(16) char smem[];     // [0,64K) W | [64K,72K) wt
    const int tid = threadIdx.x;
    const int lane = tid & 63;
    const int wv = __builtin_amdgcn_readfirstlane(tid >> 6);
    const int fr = lane & 15;
    const int fg = (lane >> 4) & 3;
    const int sw = (fr & 7) << 4;
    const int t0 = blockIdx.x * BT + wv * 32;        // wave-local 32 tokens

    // stage 4 experts (64KB) of pass `ps` into the W buffer
    auto stage = [&](int ps) {
#pragma unroll
        for (int i = 0; i < 8; ++i)
            glds16(wimg + (ps << 16) + i * 8192 + wv * 1024 + lane * 16,
                   smem + i * 8192 + wv * 1024, lane);
    };

    // ---- Phase A: X load + logits/mask + wt table (NO DMA in flight) ----
    float xv[2][2][8];
#pragma unroll
    for (int n = 0; n < 2; ++n)
#pragma unroll
        for (int kk = 0; kk < 2; ++kk) {
            const float* g = x + (size_t)(t0 + n * 16 + fr) * DH + kk * 32 + fg * 8;
            f32x4 a = *reinterpret_cast<const f32x4*>(g);
            f32x4 b = *reinterpret_cast<const f32x4*>(g + 4);
#pragma unroll
            for (int i = 0; i < 4; ++i) { xv[n][kk][i] = a[i]; xv[n][kk][4 + i] = b[i]; }
        }
    {
        float dot[2][NEXP];
#pragma unroll
        for (int n = 0; n < 2; ++n)
#pragma unroll
            for (int p = 0; p < NEXP; ++p) dot[n][p] = 0.f;
#pragma unroll
        for (int p = 0; p < NEXP; ++p)
#pragma unroll
            for (int kk = 0; kk < 2; ++kk) {
                const float* pr = proto + p * DH + kk * 32 + fg * 8;
                f32x4 p0 = *reinterpret_cast<const f32x4*>(pr);
                f32x4 p1 = *reinterpret_cast<const f32x4*>(pr + 4);
#pragma unroll
                for (int n = 0; n < 2; ++n)
#pragma unroll
                    for (int i = 0; i < 4; ++i)
                        dot[n][p] += xv[n][kk][i] * p0[i] + xv[n][kk][4 + i] * p1[i];
            }
        float lg[2][NEXP], mk[2][NEXP];
#pragma unroll
        for (int n = 0; n < 2; ++n)
#pragma unroll
            for (int p = 0; p < NEXP; ++p) {
                float v = dot[n][p];
                v += __shfl_xor(v, 16);              // butterfly over the 4 fg groups
                v += __shfl_xor(v, 32);
                lg[n][p] = v * 0.125f - gate[p];     // / sqrt(64)
                mk[n][p] = fmaxf(lg[n][p], 0.f);
            }
        // fg0: logits n=0 | fg1: logits n=1 | fg2: mask+wt n=0 | fg3: mask+wt n=1
        int ns = fg & 1;
        size_t rowb = (size_t)(t0 + ns * 16 + fr) * NEXP;
        f32x4 v0, v1;
        if (fg < 2) {
#pragma unroll
            for (int i = 0; i < 4; ++i) { v0[i] = lg[ns][i]; v1[i] = lg[ns][4 + i]; }
            *reinterpret_cast<f32x4*>(logits_out + rowb) = v0;
            *reinterpret_cast<f32x4*>(logits_out + rowb + 4) = v1;
        } else {
#pragma unroll
            for (int i = 0; i < 4; ++i) { v0[i] = mk[ns][i]; v1[i] = mk[ns][4 + i]; }
            *reinterpret_cast<f32x4*>(mask_out + rowb) = v0;
            *reinterpret_cast<f32x4*>(mask_out + rowb + 4) = v1;
            f32x4 w0, w1v;
#pragma unroll
            for (int i = 0; i < 4; ++i) {
                w0[i]  = (v0[i] > 1e-6f) ? v0[i] : 0.f;
                w1v[i] = (v1[i] > 1e-6f) ? v1[i] : 0.f;
            }
            char* wb = smem + OFF_WT + (wv * 32 + ns * 16 + fr) * 32;
            *reinterpret_cast<f32x4*>(wb) = w0;
            *reinterpret_cast<f32x4*>(wb + 16) = w1v;
        }
    }

    // ---- stage pass-0 weights (issued after logits phase) ----
    stage(0);

    // pack X->bf16 under the DMA
    short8 xb[2][2];
#pragma unroll
    for (int n = 0; n < 2; ++n)
#pragma unroll
        for (int kk = 0; kk < 2; ++kk) {
            short8 t;
#pragma unroll
            for (int j = 0; j < 8; ++j) t[j] = bfc(xv[n][kk][j]);
            xb[n][kk] = t;
        }
    __syncthreads();                                 // W pass-0 + wt table visible

    f32x4 yacc[4][2];
#pragma unroll
    for (int mt = 0; mt < 4; ++mt)
#pragma unroll
        for (int n = 0; n < 2; ++n) yacc[mt][n] = (f32x4){0.f, 0.f, 0.f, 0.f};

    const float* const wtp = reinterpret_cast<const float*>(smem + OFF_WT);

#pragma unroll 1
    for (int ps = 0; ps < 2; ++ps) {
        if (ps) {                                    // restage experts 4-7
            __syncthreads();                         // all waves done with pass-0 W
            stage(1);
            __syncthreads();                         // vmcnt drained by barrier
        }
        // ---- 4-expert loop: barrier-free ----
#pragma unroll 1
        for (int q = 0; q < 4; ++q) {
            const int p = ps * 4 + q;
            const char* sW1 = smem + (q << 14);
            const char* sW2 = sW1 + 8192;
            const float wt0 = wtp[(wv * 32 + fr) * 8 + p];        // token n=0
            const float wt1 = wtp[(wv * 32 + 16 + fr) * 8 + p];   // token n=1

#pragma unroll
            for (int h = 0; h < 2; ++h) {            // o-halves: o in [h*32, h*32+32)
                short8 w1f[2][2];
#pragma unroll
                for (int mtl = 0; mtl < 2; ++mtl)
#pragma unroll
                    for (int kk = 0; kk < 2; ++kk)
                        w1f[mtl][kk] = *reinterpret_cast<const short8*>(
                            sW1 + (h * 32 + mtl * 16 + fr) * 128 +
                            ((kk * 64 + fg * 16) ^ sw));
                f32x4 acc1[2][2];
#pragma unroll
                for (int mtl = 0; mtl < 2; ++mtl)
#pragma unroll
                    for (int n = 0; n < 2; ++n) acc1[mtl][n] = (f32x4){0.f, 0.f, 0.f, 0.f};
#pragma unroll
                for (int kk = 0; kk < 2; ++kk)
#pragma unroll
                    for (int mtl = 0; mtl < 2; ++mtl)
#pragma unroll
                        for (int n = 0; n < 2; ++n)
                            acc1[mtl][n] = __builtin_amdgcn_mfma_f32_16x16x32_bf16(
                                w1f[mtl][kk], xb[n][kk], acc1[mtl][n], 0, 0, 0);

                // silu * wt -> bf16 (GEMM2 B-frag layout, in-register)
                bf16x4 pkB[2][2];
#pragma unroll
                for (int mtl = 0; mtl < 2; ++mtl)
#pragma unroll
                    for (int n = 0; n < 2; ++n) {
                        const float wt = n ? wt1 : wt0;
                        bf16x4 t;
#pragma unroll
                        for (int r = 0; r < 4; ++r) {
                            float hd = acc1[mtl][n][r];
                            float s = hd * __builtin_amdgcn_rcpf(1.f + __expf(-hd));
                            t[r] = bfc(wt * s);
                        }
                        pkB[mtl][n] = t;
                    }

                // GEMM2 k-slices mp = 2h, 2h+1 accumulate straight into yacc
#pragma unroll
                for (int mt = 0; mt < 4; ++mt) {
                    u32x4 wq = *reinterpret_cast<const u32x4*>(
                        sW2 + (mt * 16 + fr) * 128 + ((fg * 32 + h * 16) ^ sw));
                    u32x2 lo2 = {wq[0], wq[1]}, hi2 = {wq[2], wq[3]};
                    bf16x4 wlo = __builtin_bit_cast(bf16x4, lo2);
                    bf16x4 whi = __builtin_bit_cast(bf16x4, hi2);
#pragma unroll
                    for (int n = 0; n < 2; ++n) {
                        yacc[mt][n] = MFMA16(wlo, pkB[0][n], yacc[mt][n]);
                        yacc[mt][n] = MFMA16(whi, pkB[1][n], yacc[mt][n]);
                    }
                }
            }
        }
    }

    // ---- epilogue: yacc -> LDS (W region dead) -> full-line y stores ----
    __syncthreads();                                 // all waves done with W
    char* const yb = smem + wv * 8192;               // 32 rows x 256B per wave
#pragma unroll
    for (int mt = 0; mt < 4; ++mt)
#pragma unroll
        for (int n = 0; n < 2; ++n) {
            f32x4 v;
#pragma unroll
            for (int r = 0; r < 4; ++r) v[r] = yacc[mt][n][r];
            *reinterpret_cast<f32x4*>(
                yb + (n * 16 + fr) * 256 + ((mt * 64 + fg * 16) ^ sw)) = v;
        }
    __builtin_amdgcn_s_waitcnt(0);                   // lgkm drain (per-wave region)
#pragma unroll
    for (int it = 0; it < 8; ++it) {
        const int r = it * 4 + (lane >> 4);          // row 0..31
        const int cb = (lane & 15) * 16;             // col byte within 256B row
        f32x4 v = *reinterpret_cast<const f32x4*>(yb + r * 256 + (cb ^ ((r & 7) << 4)));
        *reinterpret_cast<f32x4*>(
            reinterpret_cast<char*>(y_out) + (size_t)(t0 + r) * 256 + cb) = v;
    }
}

extern "C" void kernel_launch(void* const* d_in, const int* in_sizes, int n_in,
                              void* d_out, int out_size, void* d_ws, size_t ws_size,
                              hipStream_t stream) {
    (void)n_in; (void)out_size; (void)ws_size;
    const float* x     = (const float*)d_in[0];
    const float* proto = (const float*)d_in[1];
    const float* gate  = (const float*)d_in[2];
    const float* w1    = (const float*)d_in[3];
    const float* w2    = (const float*)d_in[4];
    float* y = (float*)d_out;
    const int S = in_sizes[0] / DH;                  // 131072
    float* logits = y + (size_t)S * DH;
    float* mask   = logits + (size_t)S * NEXP;
    unsigned char* wimg = (unsigned char*)d_ws;      // 128 KiB image

    prep_w<<<64, 256, 0, stream>>>(w1, w2, wimg);
    (void)hipFuncSetAttribute(reinterpret_cast<const void*>(spl_main),
                              hipFuncAttributeMaxDynamicSharedMemorySize, LDS_BYTES);
    spl_main<<<S / BT, THREADS, LDS_BYTES, stream>>>(x, proto, gate, wimg,
                                                     y, logits, mask);
}

// Round 8
// 55.156 us; speedup vs baseline: 1.1990x; 1.1990x over previous
//
#include <hip/hip_runtime.h>
#include <hip/hip_bf16.h>

// SparseProtoLinear: S=131072 tokens, D=64, P=8 experts.
// d_out = [y (S*64) | logits (S*8) | mask (S*8)], fp32.
//
// prep_w: fp32 W1/W2 -> bf16 image in d_ws (XOR-swizzled rows; W2 columns
//         permuted so GEMM2 A-frags read as b128).
// spl_main: 512 blocks x 512 thr, 256 tokens/block (32/wave).
//   LDS = 64KB (4 experts) + 8KB wt table -> 72KB => 2 blocks/CU
//   (16 waves/CU, 4/SIMD). launch_bounds(512,1): do NOT cap VGPR --
//   round 7's (512,4) forced a 64-VGPR cap and spilled (+86MB scratch).
//   Two passes of 4 experts; restage between passes. Expert loop itself
//   barrier-free. GEMM1 swapped (W1 x X^T, mfma 16x16x32), silu*wt packed
//   in-register -> GEMM2 (mfma 16x16x16) accumulates into yacc.
//   Epilogue: yacc -> LDS -> full-cacheline 1KB y stores.

typedef __attribute__((ext_vector_type(8))) short short8;
typedef __attribute__((ext_vector_type(4))) short bf16x4;   // HIP owns `short4`
typedef __attribute__((ext_vector_type(4))) float f32x4;
typedef __attribute__((ext_vector_type(4))) unsigned int u32x4;
typedef __attribute__((ext_vector_type(2))) unsigned int u32x2;

#define NEXP 8
#define DH 64
#define BT 256
#define THREADS 512
#define OFF_WT 65536
#define LDS_BYTES (65536 + 8192)   // 4-expert W buffer + 256x8 wt table

__device__ __forceinline__ unsigned int f2bf(float f) {
    unsigned int u = __builtin_bit_cast(unsigned int, f);
    return (u + 0x7fffu + ((u >> 16) & 1u)) >> 16;  // RTNE (prep kernel only)
}
__device__ __forceinline__ short bfc(float f) {     // compiler-lowered convert
    return (short)__bfloat16_as_ushort(__float2bfloat16(f));
}

#if __has_builtin(__builtin_amdgcn_mfma_f32_16x16x16_bf16)
#define MFMA16(a, b, c) __builtin_amdgcn_mfma_f32_16x16x16_bf16(a, b, c, 0, 0, 0)
#else
#define MFMA16(a, b, c) __builtin_amdgcn_mfma_f32_16x16x16bf16_1k(a, b, c, 0, 0, 0)
#endif

typedef const unsigned int __attribute__((address_space(1)))* gas_u32p;
typedef unsigned int __attribute__((address_space(3)))* las_u32p;

// g includes the per-lane offset; lbase is wave-uniform (HW adds lane*16).
__device__ __forceinline__ void glds16(const void* g, void* lbase, int lane) {
#if __has_builtin(__builtin_amdgcn_global_load_lds)
    (void)lane;
    __builtin_amdgcn_global_load_lds((gas_u32p)g, (las_u32p)lbase, 16, 0, 0);
#else
    *reinterpret_cast<u32x4*>(reinterpret_cast<char*>(lbase) + lane * 16) =
        *reinterpret_cast<const u32x4*>(g);
#endif
}

// ---------------- prep: weights -> bf16 swizzled image (128 KiB) ----------------
__global__ void prep_w(const float* __restrict__ w1, const float* __restrict__ w2,
                       unsigned char* __restrict__ ws) {
    int q = blockIdx.x * 256 + threadIdx.x;          // 16384 quads of 4 f32
    int mat = q >> 13;                               // 0=W1, 1=W2
    int p = (q >> 10) & 7;
    int r = (q >> 4) & 63;                           // source row (o for W1, d for W2)
    int dq = q & 15;                                 // source col quad
    const float* src = (mat ? w2 : w1) + (size_t)(((p << 6) + r) << 6) + (dq << 2);
    f32x4 v = *reinterpret_cast<const f32x4*>(src);
    u32x2 pk;
    pk[0] = f2bf(v[0]) | (f2bf(v[1]) << 16);
    pk[1] = f2bf(v[2]) | (f2bf(v[3]) << 16);
    // W1: byte col = dq*8.  W2 col-permute o=[mp|fg|j]->[fg|mp|j]:
    //   mp=dq>>2, fg=dq&3 -> byte col = fg*32 + mp*8.
    int col = mat ? (((dq & 3) << 5) | ((dq >> 2) << 3)) : (dq << 3);
    int off = (p << 14) + (mat << 13) + (r << 7) + (col ^ ((r & 7) << 4));
    *reinterpret_cast<u32x2*>(ws + off) = pk;
}

// ---------------- main fused kernel ----------------
__global__ __launch_bounds__(THREADS, 1)   // no VGPR cap; LDS gives 2 blocks/CU
void spl_main(const float* __restrict__ x, const float* __restrict__ proto,
              const float* __restrict__ gate, const unsigned char* __restrict__ wimg,
              float* __restrict__ y_out, float* __restrict__ logits_out,
              float* __restrict__ mask_out)
{
    extern __shared__ __align__(16) char smem[];     // [0,64K) W | [64K,72K) wt
    const int tid = threadIdx.x;
    const int lane = tid & 63;
    const int wv = __builtin_amdgcn_readfirstlane(tid >> 6);
    const int fr = lane & 15;
    const int fg = (lane >> 4) & 3;
    const int sw = (fr & 7) << 4;
    const int t0 = blockIdx.x * BT + wv * 32;        // wave-local 32 tokens

    // stage 4 experts (64KB) of pass `ps` into the W buffer
    auto stage = [&](int ps) {
#pragma unroll
        for (int i = 0; i < 8; ++i)
            glds16(wimg + (ps << 16) + i * 8192 + wv * 1024 + lane * 16,
                   smem + i * 8192 + wv * 1024, lane);
    };

    // ---- Phase A: X load + logits/mask + wt table (NO DMA in flight) ----
    float xv[2][2][8];
#pragma unroll
    for (int n = 0; n < 2; ++n)
#pragma unroll
        for (int kk = 0; kk < 2; ++kk) {
            const float* g = x + (size_t)(t0 + n * 16 + fr) * DH + kk * 32 + fg * 8;
            f32x4 a = *reinterpret_cast<const f32x4*>(g);
            f32x4 b = *reinterpret_cast<const f32x4*>(g + 4);
#pragma unroll
            for (int i = 0; i < 4; ++i) { xv[n][kk][i] = a[i]; xv[n][kk][4 + i] = b[i]; }
        }
    {
        float dot[2][NEXP];
#pragma unroll
        for (int n = 0; n < 2; ++n)
#pragma unroll
            for (int p = 0; p < NEXP; ++p) dot[n][p] = 0.f;
#pragma unroll
        for (int p = 0; p < NEXP; ++p)
#pragma unroll
            for (int kk = 0; kk < 2; ++kk) {
                const float* pr = proto + p * DH + kk * 32 + fg * 8;
                f32x4 p0 = *reinterpret_cast<const f32x4*>(pr);
                f32x4 p1 = *reinterpret_cast<const f32x4*>(pr + 4);
#pragma unroll
                for (int n = 0; n < 2; ++n)
#pragma unroll
                    for (int i = 0; i < 4; ++i)
                        dot[n][p] += xv[n][kk][i] * p0[i] + xv[n][kk][4 + i] * p1[i];
            }
        float lg[2][NEXP], mk[2][NEXP];
#pragma unroll
        for (int n = 0; n < 2; ++n)
#pragma unroll
            for (int p = 0; p < NEXP; ++p) {
                float v = dot[n][p];
                v += __shfl_xor(v, 16);              // butterfly over the 4 fg groups
                v += __shfl_xor(v, 32);
                lg[n][p] = v * 0.125f - gate[p];     // / sqrt(64)
                mk[n][p] = fmaxf(lg[n][p], 0.f);
            }
        // fg0: logits n=0 | fg1: logits n=1 | fg2: mask+wt n=0 | fg3: mask+wt n=1
        int ns = fg & 1;
        size_t rowb = (size_t)(t0 + ns * 16 + fr) * NEXP;
        f32x4 v0, v1;
        if (fg < 2) {
#pragma unroll
            for (int i = 0; i < 4; ++i) { v0[i] = lg[ns][i]; v1[i] = lg[ns][4 + i]; }
            *reinterpret_cast<f32x4*>(logits_out + rowb) = v0;
            *reinterpret_cast<f32x4*>(logits_out + rowb + 4) = v1;
        } else {
#pragma unroll
            for (int i = 0; i < 4; ++i) { v0[i] = mk[ns][i]; v1[i] = mk[ns][4 + i]; }
            *reinterpret_cast<f32x4*>(mask_out + rowb) = v0;
            *reinterpret_cast<f32x4*>(mask_out + rowb + 4) = v1;
            f32x4 w0, w1v;
#pragma unroll
            for (int i = 0; i < 4; ++i) {
                w0[i]  = (v0[i] > 1e-6f) ? v0[i] : 0.f;
                w1v[i] = (v1[i] > 1e-6f) ? v1[i] : 0.f;
            }
            char* wb = smem + OFF_WT + (wv * 32 + ns * 16 + fr) * 32;
            *reinterpret_cast<f32x4*>(wb) = w0;
            *reinterpret_cast<f32x4*>(wb + 16) = w1v;
        }
    }

    // ---- stage pass-0 weights (issued after logits phase) ----
    stage(0);

    // pack X->bf16 under the DMA
    short8 xb[2][2];
#pragma unroll
    for (int n = 0; n < 2; ++n)
#pragma unroll
        for (int kk = 0; kk < 2; ++kk) {
            short8 t;
#pragma unroll
            for (int j = 0; j < 8; ++j) t[j] = bfc(xv[n][kk][j]);
            xb[n][kk] = t;
        }
    __syncthreads();                                 // W pass-0 + wt table visible

    f32x4 yacc[4][2];
#pragma unroll
    for (int mt = 0; mt < 4; ++mt)
#pragma unroll
        for (int n = 0; n < 2; ++n) yacc[mt][n] = (f32x4){0.f, 0.f, 0.f, 0.f};

    const float* const wtp = reinterpret_cast<const float*>(smem + OFF_WT);

#pragma unroll 1
    for (int ps = 0; ps < 2; ++ps) {
        if (ps) {                                    // restage experts 4-7
            __syncthreads();                         // all waves done with pass-0 W
            stage(1);
            __syncthreads();                         // vmcnt drained by barrier
        }
        // ---- 4-expert loop: barrier-free ----
#pragma unroll 1
        for (int q = 0; q < 4; ++q) {
            const int p = ps * 4 + q;
            const char* sW1 = smem + (q << 14);
            const char* sW2 = sW1 + 8192;
            const float wt0 = wtp[(wv * 32 + fr) * 8 + p];        // token n=0
            const float wt1 = wtp[(wv * 32 + 16 + fr) * 8 + p];   // token n=1

#pragma unroll
            for (int h = 0; h < 2; ++h) {            // o-halves: o in [h*32, h*32+32)
                short8 w1f[2][2];
#pragma unroll
                for (int mtl = 0; mtl < 2; ++mtl)
#pragma unroll
                    for (int kk = 0; kk < 2; ++kk)
                        w1f[mtl][kk] = *reinterpret_cast<const short8*>(
                            sW1 + (h * 32 + mtl * 16 + fr) * 128 +
                            ((kk * 64 + fg * 16) ^ sw));
                f32x4 acc1[2][2];
#pragma unroll
                for (int mtl = 0; mtl < 2; ++mtl)
#pragma unroll
                    for (int n = 0; n < 2; ++n) acc1[mtl][n] = (f32x4){0.f, 0.f, 0.f, 0.f};
#pragma unroll
                for (int kk = 0; kk < 2; ++kk)
#pragma unroll
                    for (int mtl = 0; mtl < 2; ++mtl)
#pragma unroll
                        for (int n = 0; n < 2; ++n)
                            acc1[mtl][n] = __builtin_amdgcn_mfma_f32_16x16x32_bf16(
                                w1f[mtl][kk], xb[n][kk], acc1[mtl][n], 0, 0, 0);

                // silu * wt -> bf16 (GEMM2 B-frag layout, in-register)
                bf16x4 pkB[2][2];
#pragma unroll
                for (int mtl = 0; mtl < 2; ++mtl)
#pragma unroll
                    for (int n = 0; n < 2; ++n) {
                        const float wt = n ? wt1 : wt0;
                        bf16x4 t;
#pragma unroll
                        for (int r = 0; r < 4; ++r) {
                            float hd = acc1[mtl][n][r];
                            float s = hd * __builtin_amdgcn_rcpf(1.f + __expf(-hd));
                            t[r] = bfc(wt * s);
                        }
                        pkB[mtl][n] = t;
                    }

                // GEMM2 k-slices mp = 2h, 2h+1 accumulate straight into yacc
#pragma unroll
                for (int mt = 0; mt < 4; ++mt) {
                    u32x4 wq = *reinterpret_cast<const u32x4*>(
                        sW2 + (mt * 16 + fr) * 128 + ((fg * 32 + h * 16) ^ sw));
                    u32x2 lo2 = {wq[0], wq[1]}, hi2 = {wq[2], wq[3]};
                    bf16x4 wlo = __builtin_bit_cast(bf16x4, lo2);
                    bf16x4 whi = __builtin_bit_cast(bf16x4, hi2);
#pragma unroll
                    for (int n = 0; n < 2; ++n) {
                        yacc[mt][n] = MFMA16(wlo, pkB[0][n], yacc[mt][n]);
                        yacc[mt][n] = MFMA16(whi, pkB[1][n], yacc[mt][n]);
                    }
                }
            }
        }
    }

    // ---- epilogue: yacc -> LDS (W region dead) -> full-line y stores ----
    __syncthreads();                                 // all waves done with W
    char* const yb = smem + wv * 8192;               // 32 rows x 256B per wave
#pragma unroll
    for (int mt = 0; mt < 4; ++mt)
#pragma unroll
        for (int n = 0; n < 2; ++n) {
            f32x4 v;
#pragma unroll
            for (int r = 0; r < 4; ++r) v[r] = yacc[mt][n][r];
            *reinterpret_cast<f32x4*>(
                yb + (n * 16 + fr) * 256 + ((mt * 64 + fg * 16) ^ sw)) = v;
        }
    __builtin_amdgcn_s_waitcnt(0);                   // lgkm drain (per-wave region)
#pragma unroll
    for (int it = 0; it < 8; ++it) {
        const int r = it * 4 + (lane >> 4);          // row 0..31
        const int cb = (lane & 15) * 16;             // col byte within 256B row
        f32x4 v = *reinterpret_cast<const f32x4*>(yb + r * 256 + (cb ^ ((r & 7) << 4)));
        *reinterpret_cast<f32x4*>(
            reinterpret_cast<char*>(y_out) + (size_t)(t0 + r) * 256 + cb) = v;
    }
}

extern "C" void kernel_launch(void* const* d_in, const int* in_sizes, int n_in,
                              void* d_out, int out_size, void* d_ws, size_t ws_size,
                              hipStream_t stream) {
    (void)n_in; (void)out_size; (void)ws_size;
    const float* x     = (const float*)d_in[0];
    const float* proto = (const float*)d_in[1];
    const float* gate  = (const float*)d_in[2];
    const float* w1    = (const float*)d_in[3];
    const float* w2    = (const float*)d_in[4];
    float* y = (float*)d_out;
    const int S = in_sizes[0] / DH;                  // 131072
    float* logits = y + (size_t)S * DH;
    float* mask   = logits + (size_t)S * NEXP;
    unsigned char* wimg = (unsigned char*)d_ws;      // 128 KiB image

    prep_w<<<64, 256, 0, stream>>>(w1, w2, wimg);
    (void)hipFuncSetAttribute(reinterpret_cast<const void*>(spl_main),
                              hipFuncAttributeMaxDynamicSharedMemorySize, LDS_BYTES);
    spl_main<<<S / BT, THREADS, LDS_BYTES, stream>>>(x, proto, gate, wimg,
                                                     y, logits, mask);
}